// Round 8
// baseline (742.143 us; speedup 1.0000x reference)
//
#include <hip/hip_runtime.h>
#include <cmath>

static constexpr int NN  = 50000;   // nodes
static constexpr int NE  = 800000;  // edges
static constexpr int HID = 64;
static constexpr int BB  = 64;      // batch
static constexpr int TT  = 200;     // seq len
static constexpr int LH  = 128;     // lstm hidden
static constexpr int G4  = 512;     // 4*LH

static constexpr int SCB = 125;     // scan blocks
static constexpr int SCH = 400;     // elems per scan block (125*400 = 50000)

typedef _Float16 h2 __attribute__((ext_vector_type(2)));

#ifndef __has_builtin
#define __has_builtin(x) 0
#endif
#if __has_builtin(__builtin_amdgcn_fdot2)
__device__ __forceinline__ float fdot2_(h2 a, h2 b, float c) {
    return __builtin_amdgcn_fdot2(a, b, c, false);
}
#else
__device__ __forceinline__ float fdot2_(h2 a, h2 b, float c) {
    return c + (float)a.x * (float)b.x + (float)a.y * (float)b.y;
}
#endif

__device__ __forceinline__ h2 as_h2(unsigned int u) {
    union { unsigned int u; h2 h; } cv; cv.u = u; return cv.h;
}

__device__ __forceinline__ float sigmoid_fast(float x) {
    return __fdividef(1.f, 1.f + __expf(-x));
}
__device__ __forceinline__ float tanh_fast(float x) {
    return __fdividef(2.f, 1.f + __expf(-2.f * x)) - 1.f;
}

// ================= CSR build =================
__global__ __launch_bounds__(256) void hist_kernel(const int* __restrict__ dsts,
                                                   int* __restrict__ deg) {
    int i = blockIdx.x * 256 + threadIdx.x;
    if (i < NE) atomicAdd(&deg[dsts[i]], 1);
}

__global__ __launch_bounds__(512) void scan1_kernel(const int* __restrict__ deg,
                                                    int* __restrict__ loc,
                                                    int* __restrict__ bsum) {
    __shared__ int ws[8];
    const int b = blockIdx.x, t = threadIdx.x;
    const int idx = b * SCH + t;
    const int lane = t & 63, wv = t >> 6;
    int v = (t < SCH && idx < NN) ? deg[idx] : 0;
    int x = v;
    #pragma unroll
    for (int off = 1; off < 64; off <<= 1) {
        int y = __shfl_up(x, off);
        if (lane >= off) x += y;
    }
    if (lane == 63) ws[wv] = x;
    __syncthreads();
    if (t < 8) {
        int s = ws[t];
        #pragma unroll
        for (int off = 1; off < 8; off <<= 1) {
            int y = __shfl_up(s, off);
            if (t >= off) s += y;
        }
        ws[t] = s;
    }
    __syncthreads();
    const int base = wv ? ws[wv - 1] : 0;
    if (t < SCH && idx < NN) loc[idx] = base + x - v;
    if (t == 511) bsum[b] = ws[7];
}

__global__ void scan2_kernel(const int* __restrict__ bsum,
                             int* __restrict__ boff,
                             int* __restrict__ rowptr) {
    int tot = 0;
    for (int i = 0; i < SCB; ++i) { boff[i] = tot; tot += bsum[i]; }
    rowptr[NN] = tot;
}

__global__ __launch_bounds__(512) void scan3_kernel(const int* __restrict__ loc,
                                                    const int* __restrict__ boff,
                                                    int* __restrict__ rowptr,
                                                    int* __restrict__ head) {
    const int b = blockIdx.x, t = threadIdx.x;
    const int idx = b * SCH + t;
    if (t < SCH && idx < NN) {
        int r = loc[idx] + boff[b];
        rowptr[idx] = r;
        head[idx] = r;
    }
}

__global__ __launch_bounds__(256) void scatter_kernel(const int* __restrict__ srcs,
                                                      const int* __restrict__ dsts,
                                                      int* __restrict__ head,
                                                      int2* __restrict__ sorted) {
    int e = blockIdx.x * 256 + threadIdx.x;
    if (e < NE) {
        int d = dsts[e];
        int pos = atomicAdd(&head[d], 1);
        sorted[pos] = make_int2(e, srcs[e]);
    }
}

// fp32 -> fp16 convert (linear), 4 elems/thread; grid covers exactly count/4/256
__global__ __launch_bounds__(256) void cvt16_kernel(const float* __restrict__ in,
                                                    _Float16* __restrict__ o) {
    int i = blockIdx.x * 256 + threadIdx.x;   // i indexes groups of 4
    float4 v = ((const float4*)in)[i];
    union { _Float16 h[4]; ushort4 u; } pk;
    pk.h[0] = (_Float16)v.x; pk.h[1] = (_Float16)v.y;
    pk.h[2] = (_Float16)v.z; pk.h[3] = (_Float16)v.w;
    ((ushort4*)o)[i] = pk.u;
}

// ========= fused edge pass: CSR by dst, NO LDS staging =========
// wave per node, lane = output channel. Edge index is wave-uniform -> edge
// feature vector loaded via uniform (scalar-cache) loads, dotted against the
// per-lane weight row with v_dot2. h[src] gathered fp16 (128 B/edge).
__global__ __launch_bounds__(256) void edge_agg_kernel(
    const _Float16* __restrict__ h16,    // [NN][64] fp16 gather table
    const _Float16* __restrict__ ea16,   // [NE][64] fp16, ORIGINAL edge order
    const float*    __restrict__ W,      // [64][64] W[c][k]
    const float*    __restrict__ bias,   // [64]
    const int*      __restrict__ rowptr,
    const int2*     __restrict__ sorted, // (edge id, src) per sorted pos
    float*          __restrict__ agg)
{
    const int lane = threadIdx.x & 63;
    const int wid  = threadIdx.x >> 6;

    h2 w2[32];
    {
        const float4* wf = (const float4*)(W + lane * 64);
        #pragma unroll
        for (int k4 = 0; k4 < 16; ++k4) {
            float4 v = wf[k4];
            h2 a; a.x = (_Float16)v.x; a.y = (_Float16)v.y;
            h2 b; b.x = (_Float16)v.z; b.y = (_Float16)v.w;
            w2[2*k4] = a; w2[2*k4+1] = b;
        }
    }
    const float bc = bias[lane];

    const int gw = blockIdx.x * 4 + wid;
    const int nw = gridDim.x * 4;
    for (int n = gw; n < NN; n += nw) {
        const int ofs = rowptr[n];
        const int dg  = rowptr[n + 1] - ofs;
        float acc = 0.f;
        #pragma unroll 2
        for (int i = 0; i < dg; ++i) {
            int2 es = sorted[ofs + i];                       // uniform addr
            const int eo = __builtin_amdgcn_readfirstlane(es.x);
            const int sj = __builtin_amdgcn_readfirstlane(es.y);
            // issue the h gather early (vector, 2B/lane coalesced)
            float hvv = (float)h16[(size_t)sj * HID + lane];
            const uint4* ep = (const uint4*)(ea16 + (size_t)eo * HID);
            uint4 q0 = ep[0], q1 = ep[1], q2 = ep[2], q3 = ep[3];
            uint4 q4 = ep[4], q5 = ep[5], q6 = ep[6], q7 = ep[7];
            float aE = bc;
            aE = fdot2_(as_h2(q0.x), w2[ 0], aE);
            aE = fdot2_(as_h2(q0.y), w2[ 1], aE);
            aE = fdot2_(as_h2(q0.z), w2[ 2], aE);
            aE = fdot2_(as_h2(q0.w), w2[ 3], aE);
            aE = fdot2_(as_h2(q1.x), w2[ 4], aE);
            aE = fdot2_(as_h2(q1.y), w2[ 5], aE);
            aE = fdot2_(as_h2(q1.z), w2[ 6], aE);
            aE = fdot2_(as_h2(q1.w), w2[ 7], aE);
            aE = fdot2_(as_h2(q2.x), w2[ 8], aE);
            aE = fdot2_(as_h2(q2.y), w2[ 9], aE);
            aE = fdot2_(as_h2(q2.z), w2[10], aE);
            aE = fdot2_(as_h2(q2.w), w2[11], aE);
            aE = fdot2_(as_h2(q3.x), w2[12], aE);
            aE = fdot2_(as_h2(q3.y), w2[13], aE);
            aE = fdot2_(as_h2(q3.z), w2[14], aE);
            aE = fdot2_(as_h2(q3.w), w2[15], aE);
            aE = fdot2_(as_h2(q4.x), w2[16], aE);
            aE = fdot2_(as_h2(q4.y), w2[17], aE);
            aE = fdot2_(as_h2(q4.z), w2[18], aE);
            aE = fdot2_(as_h2(q4.w), w2[19], aE);
            aE = fdot2_(as_h2(q5.x), w2[20], aE);
            aE = fdot2_(as_h2(q5.y), w2[21], aE);
            aE = fdot2_(as_h2(q5.z), w2[22], aE);
            aE = fdot2_(as_h2(q5.w), w2[23], aE);
            aE = fdot2_(as_h2(q6.x), w2[24], aE);
            aE = fdot2_(as_h2(q6.y), w2[25], aE);
            aE = fdot2_(as_h2(q6.z), w2[26], aE);
            aE = fdot2_(as_h2(q6.w), w2[27], aE);
            aE = fdot2_(as_h2(q7.x), w2[28], aE);
            aE = fdot2_(as_h2(q7.y), w2[29], aE);
            aE = fdot2_(as_h2(q7.z), w2[30], aE);
            aE = fdot2_(as_h2(q7.w), w2[31], aE);
            float m = aE + hvv;
            acc += m > 0.f ? m : 0.f;
        }
        agg[(size_t)n * HID + lane] = acc;
    }
}

// ---------------- node pass: fp16 LDS staging (halves DS + VALU) ----------------
__global__ __launch_bounds__(256) void node_kernel(
    const float* __restrict__ h_in,
    const float* __restrict__ agg,
    const float* __restrict__ W1, const float* __restrict__ b1,
    const float* __restrict__ W2, const float* __restrict__ b2,
    const float* __restrict__ epsp,
    const float* __restrict__ lnS, const float* __restrict__ lnB,
    float*       __restrict__ h_out,
    _Float16*    __restrict__ h16_out)   // may be null
{
    __shared__ _Float16 zbuf[4][64];
    __shared__ _Float16 tbuf[4][64];
    const int lane = threadIdx.x & 63;
    const int wid  = threadIdx.x >> 6;

    h2 w1h[32], w2h[32];
    {
        const float4* wf1 = (const float4*)(W1 + lane * 64);
        const float4* wf2 = (const float4*)(W2 + lane * 64);
        #pragma unroll
        for (int k4 = 0; k4 < 16; ++k4) {
            float4 a = wf1[k4], b = wf2[k4];
            h2 pa; pa.x = (_Float16)a.x; pa.y = (_Float16)a.y;
            h2 pb; pb.x = (_Float16)a.z; pb.y = (_Float16)a.w;
            w1h[2*k4] = pa; w1h[2*k4+1] = pb;
            h2 pc; pc.x = (_Float16)b.x; pc.y = (_Float16)b.y;
            h2 pd; pd.x = (_Float16)b.z; pd.y = (_Float16)b.w;
            w2h[2*k4] = pc; w2h[2*k4+1] = pd;
        }
    }
    const float b1c = b1[lane], b2c = b2[lane];
    const float sC = lnS[lane], bC = lnB[lane];
    const float epv = 1.f + epsp[0];

    const int gw = blockIdx.x * 4 + wid;
    const int nw = gridDim.x * 4;
    for (int n = gw; n < NN; n += nw) {
        float z = epv * h_in[(size_t)n*HID + lane] + agg[(size_t)n*HID + lane];
        zbuf[wid][lane] = (_Float16)z;
        asm volatile("s_waitcnt lgkmcnt(0)" ::: "memory");
        float acc = b1c;
        {
            const uint4* zf = (const uint4*)&zbuf[wid][0];
            #pragma unroll
            for (int k = 0; k < 8; ++k) {
                uint4 u = zf[k];
                acc = fdot2_(as_h2(u.x), w1h[4*k+0], acc);
                acc = fdot2_(as_h2(u.y), w1h[4*k+1], acc);
                acc = fdot2_(as_h2(u.z), w1h[4*k+2], acc);
                acc = fdot2_(as_h2(u.w), w1h[4*k+3], acc);
            }
        }
        acc = acc > 0.f ? acc : 0.f;
        tbuf[wid][lane] = (_Float16)acc;
        asm volatile("s_waitcnt lgkmcnt(0)" ::: "memory");
        float acc2 = b2c;
        {
            const uint4* tf = (const uint4*)&tbuf[wid][0];
            #pragma unroll
            for (int k = 0; k < 8; ++k) {
                uint4 u = tf[k];
                acc2 = fdot2_(as_h2(u.x), w2h[4*k+0], acc2);
                acc2 = fdot2_(as_h2(u.y), w2h[4*k+1], acc2);
                acc2 = fdot2_(as_h2(u.z), w2h[4*k+2], acc2);
                acc2 = fdot2_(as_h2(u.w), w2h[4*k+3], acc2);
            }
        }
        float s1 = acc2, s2 = acc2 * acc2;
        #pragma unroll
        for (int off = 32; off >= 1; off >>= 1) {
            s1 += __shfl_xor(s1, off);
            s2 += __shfl_xor(s2, off);
        }
        float mu  = s1 * (1.f/64.f);
        float var = s2 * (1.f/64.f) - mu * mu;
        float r   = rsqrtf(var + 1e-5f);
        float o   = (acc2 - mu) * r * sC + bC;
        float ov  = o > 0.f ? o : 0.f;
        h_out[(size_t)n*HID + lane] = ov;
        if (h16_out) h16_out[(size_t)n*HID + lane] = (_Float16)ov;
    }
}

// ---------------- prep: W2T transpose + selp = b_ih + sel @ W_ih[:, :64]^T ----------------
// stored PERMUTED to lstm thread order: gate g -> pos = (j<<2)|((gt&1)<<1)|(gt>>1)
__global__ __launch_bounds__(512) void prep_kernel(
    const float* __restrict__ Wih,   // [512][96]
    const float* __restrict__ bih,   // [512]
    const float* __restrict__ h2v,   // [NN][64]
    const int*   __restrict__ nidx,  // [64]
    float*       __restrict__ W2T,   // [32][512] permuted cols
    float*       __restrict__ selp)  // [64][512] permuted cols
{
    const int g  = threadIdx.x;                       // gate index 0..511
    const int j_ = g & 127, gt_ = g >> 7;
    const int pos = (j_ << 2) | ((gt_ & 1) << 1) | (gt_ >> 1);
    if (blockIdx.x == BB) {
        #pragma unroll
        for (int k = 0; k < 32; ++k)
            W2T[k * G4 + pos] = Wih[g * 96 + 64 + k];
    } else {
        const int b = blockIdx.x;
        __shared__ float hrow[64];
        if (g < 64) hrow[g] = h2v[(size_t)nidx[b] * HID + g];
        __syncthreads();
        float acc = bih[g];
        #pragma unroll
        for (int k = 0; k < 64; ++k)
            acc = fmaf(hrow[k], Wih[g * 96 + k], acc);
        selp[b * G4 + pos] = acc;
    }
}

// ---------------- xp[t][b][pos] = selp[b][pos] + x_seq[b][t] @ W2T[:,pos] ----------------
__global__ __launch_bounds__(512) void xp_kernel(
    const float* __restrict__ xseq,  // [B][T][32]
    const float* __restrict__ selp,  // [B][512] permuted
    const float* __restrict__ W2T,   // [32][512] permuted
    float*       __restrict__ xp)    // [T][B][512] permuted
{
    const int g   = threadIdx.x;
    const int row = blockIdx.x;      // row = t*64 + b
    const int t   = row >> 6;
    const int b   = row & 63;
    __shared__ float xs[32];
    if (g < 32) xs[g] = xseq[((size_t)b * TT + t) * 32 + g];
    __syncthreads();
    float acc = selp[b * G4 + g];
    #pragma unroll
    for (int k = 0; k < 32; ++k)
        acc = fmaf(xs[k], W2T[k * G4 + g], acc);
    xp[(size_t)row * G4 + g] = acc;
}

// ---------------- LSTM recurrence + final LN + fc ----------------
// 64 blocks x 256 threads (4 waves). Thread t owns TWO gates of hidden unit
// j=t>>1: types p=t&1 and p+2. Halving the wave count halves the per-CU DS
// broadcast cost (the round-5 bottleneck); the doubled per-thread dot work
// runs on 4 SIMDs in parallel. Gates exchanged with partner lane^1 via
// shfl_xor; c replicated x2; ONE barrier/step, double-buffered fp16 h.
__global__ __launch_bounds__(256) void lstm_kernel(
    const float* __restrict__ xp,    // [T][B][512] thread-order
    const float* __restrict__ Whh,   // [512][128]
    const float* __restrict__ bhh,   // [512]
    const float* __restrict__ lnS, const float* __restrict__ lnB,  // [128]
    const float* __restrict__ fcW,   // [1][128]
    const float* __restrict__ fcb,   // [1]
    float*       __restrict__ out)   // [64]
{
    const int t  = threadIdx.x;      // 0..255
    const int b  = blockIdx.x;
    const int p  = t & 1;
    const int j  = t >> 1;           // hidden unit 0..127
    const int gate0 = p * LH + j;            // type p   (i or f)
    const int gate1 = (p + 2) * LH + j;      // type p+2 (g or o)

    h2 wA[64], wB[64];
    {
        const float4* wf0 = (const float4*)(Whh + (size_t)gate0 * LH);
        const float4* wf1 = (const float4*)(Whh + (size_t)gate1 * LH);
        #pragma unroll
        for (int k4 = 0; k4 < 32; ++k4) {
            float4 v = wf0[k4];
            h2 a; a.x = (_Float16)v.x; a.y = (_Float16)v.y;
            h2 c2; c2.x = (_Float16)v.z; c2.y = (_Float16)v.w;
            wA[2*k4] = a; wA[2*k4+1] = c2;
            float4 u = wf1[k4];
            h2 d; d.x = (_Float16)u.x; d.y = (_Float16)u.y;
            h2 e2; e2.x = (_Float16)u.z; e2.y = (_Float16)u.w;
            wB[2*k4] = d; wB[2*k4+1] = e2;
        }
    }
    const float bg0 = bhh[gate0];
    const float bg1 = bhh[gate1];
    // act0 (type p): sigmoid. act1 (type p+2): p==0 -> tanh, p==1 -> sigmoid.
    const float s1_ = (p == 0) ? 2.f : 1.f;
    const float a1_ = (p == 0) ? 2.f : 1.f;
    const float d1_ = (p == 0) ? -1.f : 0.f;

    __shared__ _Float16 hb[2][LH];        // fp16 h, double buffered
    __shared__ float h_final[LH];
    if (t < 64) ((unsigned int*)&hb[0][0])[t] = 0u;
    float c = 0.f;
    float h_last = 0.f;
    __syncthreads();

    float2 xv = ((const float2*)(xp + (size_t)b * G4))[t];   // t=0 slice

    auto step = [&](const _Float16* hbR, _Float16* hbW, int ts) {
        const int tn = (ts + 1 < TT) ? ts + 1 : ts;
        const float2 xn = ((const float2*)(xp + ((size_t)tn * BB + b) * G4))[t];

        float a0 = 0.f, a1 = 0.f, a2 = 0.f, a3 = 0.f;
        float e0 = 0.f, e1 = 0.f, e2 = 0.f, e3 = 0.f;
        const uint4* hb4 = (const uint4*)hbR;
        #pragma unroll
        for (int k = 0; k < 16; ++k) {
            uint4 u = hb4[k];
            h2 p0 = as_h2(u.x), p1 = as_h2(u.y), p2 = as_h2(u.z), p3 = as_h2(u.w);
            a0 = fdot2_(p0, wA[4*k+0], a0);
            a1 = fdot2_(p1, wA[4*k+1], a1);
            a2 = fdot2_(p2, wA[4*k+2], a2);
            a3 = fdot2_(p3, wA[4*k+3], a3);
            e0 = fdot2_(p0, wB[4*k+0], e0);
            e1 = fdot2_(p1, wB[4*k+1], e1);
            e2 = fdot2_(p2, wB[4*k+2], e2);
            e3 = fdot2_(p3, wB[4*k+3], e3);
        }
        float g0 = xv.x + bg0 + ((a0 + a1) + (a2 + a3));
        float g1 = xv.y + bg1 + ((e0 + e1) + (e2 + e3));

        float act0 = sigmoid_fast(g0);                                  // i or f
        float act1 = fmaf(a1_, __fdividef(1.f, 1.f + __expf(-s1_ * g1)), d1_); // g or o

        float o0 = __shfl_xor(act0, 1);
        float o1 = __shfl_xor(act1, 1);
        float iv = p ? o0 : act0;
        float fv = p ? act0 : o0;
        float gv = p ? o1 : act1;
        float ov = p ? act1 : o1;

        c = fmaf(fv, c, iv * gv);
        h_last = ov * tanh_fast(c);

        if (p == 0) hbW[j] = (_Float16)h_last;    // ds_write_b16, even lanes
        __syncthreads();

        xv = xn;
    };

    for (int ts = 0; ts < TT; ts += 2) {
        step(&hb[0][0], &hb[1][0], ts);
        step(&hb[1][0], &hb[0][0], ts + 1);
    }

    // epilogue: stash fp32 h once, then layernorm over h (128) + fc -> out[b]
    if (p == 0) h_final[j] = h_last;
    __syncthreads();
    if (t < 64) {
        float h0 = h_final[t], h1 = h_final[t + 64];
        float s1 = h0 + h1, s2 = h0*h0 + h1*h1;
        #pragma unroll
        for (int off = 32; off >= 1; off >>= 1) {
            s1 += __shfl_xor(s1, off);
            s2 += __shfl_xor(s2, off);
        }
        float mu  = s1 * (1.f/128.f);
        float var = s2 * (1.f/128.f) - mu * mu;
        float rr  = rsqrtf(var + 1e-5f);
        float pv = ((h0 - mu)*rr*lnS[t]      + lnB[t])      * fcW[t]
                 + ((h1 - mu)*rr*lnS[t + 64] + lnB[t + 64]) * fcW[t + 64];
        #pragma unroll
        for (int off = 32; off >= 1; off >>= 1) pv += __shfl_xor(pv, off);
        if (t == 0) out[b] = pv + fcb[0];
    }
}

extern "C" void kernel_launch(void* const* d_in, const int* in_sizes, int n_in,
                              void* d_out, int out_size, void* d_ws, size_t ws_size,
                              hipStream_t stream) {
    const float* x     = (const float*)d_in[0];
    const float* ea    = (const float*)d_in[1];
    const float* xseq  = (const float*)d_in[2];
    const float* linW  = (const float*)d_in[3];
    const float* linB  = (const float*)d_in[4];
    const float* mW1   = (const float*)d_in[5];
    const float* mb1   = (const float*)d_in[6];
    const float* mW2   = (const float*)d_in[7];
    const float* mb2   = (const float*)d_in[8];
    const float* eps   = (const float*)d_in[9];
    const float* lnS   = (const float*)d_in[10];
    const float* lnB   = (const float*)d_in[11];
    const float* Wih   = (const float*)d_in[12];
    const float* Whh   = (const float*)d_in[13];
    const float* bih   = (const float*)d_in[14];
    const float* bhh   = (const float*)d_in[15];
    const float* llnS  = (const float*)d_in[16];
    const float* llnB  = (const float*)d_in[17];
    const float* fcW   = (const float*)d_in[18];
    const float* fcb   = (const float*)d_in[19];
    const int*   eidx  = (const int*)d_in[20];
    const int*   nidx  = (const int*)d_in[21];
    float* out = (float*)d_out;

    const int* srcs = eidx;
    const int* dsts = eidx + NE;

    // workspace layout
    float* ws   = (float*)d_ws;
    float* agg  = ws;                              // NN*64
    float* h1   = agg  + (size_t)NN * HID;
    float* h2m  = h1   + (size_t)NN * HID;
    float* selp = h2m  + (size_t)NN * HID;         // BB*G4
    float* W2T  = selp + (size_t)BB * G4;          // 32*G4
    float* xp   = W2T  + (size_t)32 * G4;          // TT*BB*G4
    int*   deg    = (int*)(xp + (size_t)TT * BB * G4);  // NN
    int*   rowptr = deg + NN;                      // NN+1
    int*   head   = rowptr + NN + 2;               // NN
    int*   loc    = head + NN;                     // NN
    int*   bsum   = loc + NN;                      // SCB
    int*   boff   = bsum + SCB + 3;                // SCB
    uintptr_t ip = (uintptr_t)(boff + SCB + 3);
    ip = (ip + 15) & ~(uintptr_t)15;
    int2*  sorted = (int2*)ip;                     // NE (edge id, src)
    _Float16* ea16  = (_Float16*)(sorted + NE);    // NE*64 halfs = 102.4 MB
    _Float16* x16   = ea16 + (size_t)NE * HID;     // NN*64 halfs
    _Float16* h1_16 = x16 + (size_t)NN * HID;      // NN*64 halfs

    // ---- CSR build + fp16 tables (shared by both layers) ----
    hipMemsetAsync(deg, 0, (size_t)NN * sizeof(int), stream);
    hist_kernel<<<(NE + 255) / 256, 256, 0, stream>>>(dsts, deg);
    scan1_kernel<<<SCB, 512, 0, stream>>>(deg, loc, bsum);
    scan2_kernel<<<1, 1, 0, stream>>>(bsum, boff, rowptr);
    scan3_kernel<<<SCB, 512, 0, stream>>>(loc, boff, rowptr, head);
    scatter_kernel<<<(NE + 255) / 256, 256, 0, stream>>>(srcs, dsts, head, sorted);
    cvt16_kernel<<<NE * HID / 4 / 256, 256, 0, stream>>>(ea, ea16);
    cvt16_kernel<<<NN * HID / 4 / 256, 256, 0, stream>>>(x, x16);

    // ---- layer 0 ----
    edge_agg_kernel<<<2048, 256, 0, stream>>>(x16, ea16, linW, linB, rowptr, sorted, agg);
    node_kernel<<<512, 256, 0, stream>>>(x, agg, mW1, mb1, mW2, mb2, eps, lnS, lnB, h1, h1_16);
    // ---- layer 1 ----
    edge_agg_kernel<<<2048, 256, 0, stream>>>(h1_16, ea16, linW + 64*64, linB + 64, rowptr, sorted, agg);
    node_kernel<<<512, 256, 0, stream>>>(h1, agg, mW1 + 64*64, mb1 + 64, mW2 + 64*64, mb2 + 64,
                                         eps + 1, lnS + 64, lnB + 64, h2m, (_Float16*)nullptr);
    // ---- LSTM input projection (permuted to lstm thread order) ----
    prep_kernel<<<BB + 1, 512, 0, stream>>>(Wih, bih, h2m, nidx, W2T, selp);
    xp_kernel<<<TT * BB, 512, 0, stream>>>(xseq, selp, W2T, xp);
    // ---- LSTM recurrence + head (256 threads, 2 gates/thread) ----
    lstm_kernel<<<BB, 256, 0, stream>>>(xp, Whh, bhh, llnS, llnB, fcW, fcb, out);
}

// Round 9
// 715.405 us; speedup vs baseline: 1.0374x; 1.0374x over previous
//
#include <hip/hip_runtime.h>
#include <cmath>

static constexpr int NN  = 50000;   // nodes
static constexpr int NE  = 800000;  // edges
static constexpr int HID = 64;
static constexpr int BB  = 64;      // batch
static constexpr int TT  = 200;     // seq len
static constexpr int LH  = 128;     // lstm hidden
static constexpr int G4  = 512;     // 4*LH

static constexpr int SCB = 125;     // scan blocks
static constexpr int SCH = 400;     // elems per scan block (125*400 = 50000)

typedef _Float16 h2 __attribute__((ext_vector_type(2)));

#ifndef __has_builtin
#define __has_builtin(x) 0
#endif
#if __has_builtin(__builtin_amdgcn_fdot2)
__device__ __forceinline__ float fdot2_(h2 a, h2 b, float c) {
    return __builtin_amdgcn_fdot2(a, b, c, false);
}
#else
__device__ __forceinline__ float fdot2_(h2 a, h2 b, float c) {
    return c + (float)a.x * (float)b.x + (float)a.y * (float)b.y;
}
#endif

__device__ __forceinline__ h2 as_h2(unsigned int u) {
    union { unsigned int u; h2 h; } cv; cv.u = u; return cv.h;
}

__device__ __forceinline__ float sigmoid_fast(float x) {
    return __fdividef(1.f, 1.f + __expf(-x));
}
__device__ __forceinline__ float tanh_fast(float x) {
    return __fdividef(2.f, 1.f + __expf(-2.f * x)) - 1.f;
}

// ================= CSR build =================
__global__ __launch_bounds__(256) void hist_kernel(const int* __restrict__ dsts,
                                                   int* __restrict__ deg) {
    int i = blockIdx.x * 256 + threadIdx.x;
    if (i < NE) atomicAdd(&deg[dsts[i]], 1);
}

__global__ __launch_bounds__(512) void scan1_kernel(const int* __restrict__ deg,
                                                    int* __restrict__ loc,
                                                    int* __restrict__ bsum) {
    __shared__ int ws[8];
    const int b = blockIdx.x, t = threadIdx.x;
    const int idx = b * SCH + t;
    const int lane = t & 63, wv = t >> 6;
    int v = (t < SCH && idx < NN) ? deg[idx] : 0;
    int x = v;
    #pragma unroll
    for (int off = 1; off < 64; off <<= 1) {
        int y = __shfl_up(x, off);
        if (lane >= off) x += y;
    }
    if (lane == 63) ws[wv] = x;
    __syncthreads();
    if (t < 8) {
        int s = ws[t];
        #pragma unroll
        for (int off = 1; off < 8; off <<= 1) {
            int y = __shfl_up(s, off);
            if (t >= off) s += y;
        }
        ws[t] = s;
    }
    __syncthreads();
    const int base = wv ? ws[wv - 1] : 0;
    if (t < SCH && idx < NN) loc[idx] = base + x - v;
    if (t == 511) bsum[b] = ws[7];
}

__global__ void scan2_kernel(const int* __restrict__ bsum,
                             int* __restrict__ boff,
                             int* __restrict__ rowptr) {
    int tot = 0;
    for (int i = 0; i < SCB; ++i) { boff[i] = tot; tot += bsum[i]; }
    rowptr[NN] = tot;
}

__global__ __launch_bounds__(512) void scan3_kernel(const int* __restrict__ loc,
                                                    const int* __restrict__ boff,
                                                    int* __restrict__ rowptr,
                                                    int* __restrict__ head) {
    const int b = blockIdx.x, t = threadIdx.x;
    const int idx = b * SCH + t;
    if (t < SCH && idx < NN) {
        int r = loc[idx] + boff[b];
        rowptr[idx] = r;
        head[idx] = r;
    }
}

__global__ __launch_bounds__(256) void scatter_kernel(const int* __restrict__ srcs,
                                                      const int* __restrict__ dsts,
                                                      int* __restrict__ head,
                                                      int* __restrict__ perm,
                                                      int* __restrict__ ssrc) {
    int e = blockIdx.x * 256 + threadIdx.x;
    if (e < NE) {
        int d = dsts[e];
        int pos = atomicAdd(&head[d], 1);
        perm[e] = pos;
        ssrc[pos] = srcs[e];
    }
}

// permute edge_attr into dst-sorted order, fp32 -> fp16 (one-time, both layers reuse)
__global__ __launch_bounds__(256) void permute_kernel(const float* __restrict__ ea,
                                                      const int* __restrict__ perm,
                                                      ushort4* __restrict__ easort) {
    const int lane = threadIdx.x & 63, wid = threadIdx.x >> 6;
    const int slot = lane >> 4, hw = lane & 15;
    const int e = (blockIdx.x * 4 + wid) * 4 + slot;
    if (e < NE) {
        const int p = perm[e];
        float4 v = ((const float4*)ea)[(size_t)e * 16 + hw];
        union { _Float16 h[4]; ushort4 u; } pk;
        pk.h[0] = (_Float16)v.x; pk.h[1] = (_Float16)v.y;
        pk.h[2] = (_Float16)v.z; pk.h[3] = (_Float16)v.w;
        easort[(size_t)p * 16 + hw] = pk.u;
    }
}

// fp32 -> fp16 convert (linear), 4 elems/thread
__global__ __launch_bounds__(256) void cvt16_kernel(const float* __restrict__ in,
                                                    _Float16* __restrict__ o) {
    int i = blockIdx.x * 256 + threadIdx.x;
    float4 v = ((const float4*)in)[i];
    union { _Float16 h[4]; ushort4 u; } pk;
    pk.h[0] = (_Float16)v.x; pk.h[1] = (_Float16)v.y;
    pk.h[2] = (_Float16)v.z; pk.h[3] = (_Float16)v.w;
    ((ushort4*)o)[i] = pk.u;
}

// ========= fused edge pass: dst-sorted easort, NO LDS, broadcast loads =========
// wave per node, lane = output channel. Edge rows are CONSECUTIVE in easort,
// read as wave-uniform broadcast loads (one 128-B line each, streaming).
// h[src] gathered fp16 coalesced (128 B/edge from the 6.4 MB table).
__global__ __launch_bounds__(256) void edge_agg_kernel(
    const _Float16* __restrict__ h16,    // [NN][64] fp16 gather table
    const _Float16* __restrict__ easort, // [NE][64] fp16, DST-SORTED order
    const float*    __restrict__ W,      // [64][64] W[c][k]
    const float*    __restrict__ bias,   // [64]
    const int*      __restrict__ rowptr,
    const int*      __restrict__ ssrc,   // src per sorted pos
    float*          __restrict__ agg)
{
    const int lane = threadIdx.x & 63;
    const int wid  = threadIdx.x >> 6;

    h2 w2[32];
    {
        const float4* wf = (const float4*)(W + lane * 64);
        #pragma unroll
        for (int k4 = 0; k4 < 16; ++k4) {
            float4 v = wf[k4];
            h2 a; a.x = (_Float16)v.x; a.y = (_Float16)v.y;
            h2 b; b.x = (_Float16)v.z; b.y = (_Float16)v.w;
            w2[2*k4] = a; w2[2*k4+1] = b;
        }
    }
    const float bc = bias[lane];

    const int gw = blockIdx.x * 4 + wid;
    const int nw = gridDim.x * 4;
    for (int n = gw; n < NN; n += nw) {
        const int ofs = __builtin_amdgcn_readfirstlane(rowptr[n]);
        const int dg  = __builtin_amdgcn_readfirstlane(rowptr[n + 1]) - ofs;
        float acc = 0.f;
        #pragma unroll 2
        for (int i = 0; i < dg; ++i) {
            const int pos = ofs + i;
            const int sj = __builtin_amdgcn_readfirstlane(ssrc[pos]);
            // h gather issued early (coalesced 2B/lane)
            float hvv = (float)h16[(size_t)sj * HID + lane];
            const uint4* ep = (const uint4*)(easort + (size_t)pos * HID);
            uint4 q0 = ep[0], q1 = ep[1], q2 = ep[2], q3 = ep[3];
            uint4 q4 = ep[4], q5 = ep[5], q6 = ep[6], q7 = ep[7];
            float aE = bc;
            aE = fdot2_(as_h2(q0.x), w2[ 0], aE);
            aE = fdot2_(as_h2(q0.y), w2[ 1], aE);
            aE = fdot2_(as_h2(q0.z), w2[ 2], aE);
            aE = fdot2_(as_h2(q0.w), w2[ 3], aE);
            aE = fdot2_(as_h2(q1.x), w2[ 4], aE);
            aE = fdot2_(as_h2(q1.y), w2[ 5], aE);
            aE = fdot2_(as_h2(q1.z), w2[ 6], aE);
            aE = fdot2_(as_h2(q1.w), w2[ 7], aE);
            aE = fdot2_(as_h2(q2.x), w2[ 8], aE);
            aE = fdot2_(as_h2(q2.y), w2[ 9], aE);
            aE = fdot2_(as_h2(q2.z), w2[10], aE);
            aE = fdot2_(as_h2(q2.w), w2[11], aE);
            aE = fdot2_(as_h2(q3.x), w2[12], aE);
            aE = fdot2_(as_h2(q3.y), w2[13], aE);
            aE = fdot2_(as_h2(q3.z), w2[14], aE);
            aE = fdot2_(as_h2(q3.w), w2[15], aE);
            aE = fdot2_(as_h2(q4.x), w2[16], aE);
            aE = fdot2_(as_h2(q4.y), w2[17], aE);
            aE = fdot2_(as_h2(q4.z), w2[18], aE);
            aE = fdot2_(as_h2(q4.w), w2[19], aE);
            aE = fdot2_(as_h2(q5.x), w2[20], aE);
            aE = fdot2_(as_h2(q5.y), w2[21], aE);
            aE = fdot2_(as_h2(q5.z), w2[22], aE);
            aE = fdot2_(as_h2(q5.w), w2[23], aE);
            aE = fdot2_(as_h2(q6.x), w2[24], aE);
            aE = fdot2_(as_h2(q6.y), w2[25], aE);
            aE = fdot2_(as_h2(q6.z), w2[26], aE);
            aE = fdot2_(as_h2(q6.w), w2[27], aE);
            aE = fdot2_(as_h2(q7.x), w2[28], aE);
            aE = fdot2_(as_h2(q7.y), w2[29], aE);
            aE = fdot2_(as_h2(q7.z), w2[30], aE);
            aE = fdot2_(as_h2(q7.w), w2[31], aE);
            float m = aE + hvv;
            acc += m > 0.f ? m : 0.f;
        }
        agg[(size_t)n * HID + lane] = acc;
    }
}

// ---------------- node pass: fp16 LDS staging ----------------
__global__ __launch_bounds__(256) void node_kernel(
    const float* __restrict__ h_in,
    const float* __restrict__ agg,
    const float* __restrict__ W1, const float* __restrict__ b1,
    const float* __restrict__ W2, const float* __restrict__ b2,
    const float* __restrict__ epsp,
    const float* __restrict__ lnS, const float* __restrict__ lnB,
    float*       __restrict__ h_out,
    _Float16*    __restrict__ h16_out)   // may be null
{
    __shared__ _Float16 zbuf[4][64];
    __shared__ _Float16 tbuf[4][64];
    const int lane = threadIdx.x & 63;
    const int wid  = threadIdx.x >> 6;

    h2 w1h[32], w2h[32];
    {
        const float4* wf1 = (const float4*)(W1 + lane * 64);
        const float4* wf2 = (const float4*)(W2 + lane * 64);
        #pragma unroll
        for (int k4 = 0; k4 < 16; ++k4) {
            float4 a = wf1[k4], b = wf2[k4];
            h2 pa; pa.x = (_Float16)a.x; pa.y = (_Float16)a.y;
            h2 pb; pb.x = (_Float16)a.z; pb.y = (_Float16)a.w;
            w1h[2*k4] = pa; w1h[2*k4+1] = pb;
            h2 pc; pc.x = (_Float16)b.x; pc.y = (_Float16)b.y;
            h2 pd; pd.x = (_Float16)b.z; pd.y = (_Float16)b.w;
            w2h[2*k4] = pc; w2h[2*k4+1] = pd;
        }
    }
    const float b1c = b1[lane], b2c = b2[lane];
    const float sC = lnS[lane], bC = lnB[lane];
    const float epv = 1.f + epsp[0];

    const int gw = blockIdx.x * 4 + wid;
    const int nw = gridDim.x * 4;
    for (int n = gw; n < NN; n += nw) {
        float z = epv * h_in[(size_t)n*HID + lane] + agg[(size_t)n*HID + lane];
        zbuf[wid][lane] = (_Float16)z;
        asm volatile("s_waitcnt lgkmcnt(0)" ::: "memory");
        float acc = b1c;
        {
            const uint4* zf = (const uint4*)&zbuf[wid][0];
            #pragma unroll
            for (int k = 0; k < 8; ++k) {
                uint4 u = zf[k];
                acc = fdot2_(as_h2(u.x), w1h[4*k+0], acc);
                acc = fdot2_(as_h2(u.y), w1h[4*k+1], acc);
                acc = fdot2_(as_h2(u.z), w1h[4*k+2], acc);
                acc = fdot2_(as_h2(u.w), w1h[4*k+3], acc);
            }
        }
        acc = acc > 0.f ? acc : 0.f;
        tbuf[wid][lane] = (_Float16)acc;
        asm volatile("s_waitcnt lgkmcnt(0)" ::: "memory");
        float acc2 = b2c;
        {
            const uint4* tf = (const uint4*)&tbuf[wid][0];
            #pragma unroll
            for (int k = 0; k < 8; ++k) {
                uint4 u = tf[k];
                acc2 = fdot2_(as_h2(u.x), w2h[4*k+0], acc2);
                acc2 = fdot2_(as_h2(u.y), w2h[4*k+1], acc2);
                acc2 = fdot2_(as_h2(u.z), w2h[4*k+2], acc2);
                acc2 = fdot2_(as_h2(u.w), w2h[4*k+3], acc2);
            }
        }
        float s1 = acc2, s2 = acc2 * acc2;
        #pragma unroll
        for (int off = 32; off >= 1; off >>= 1) {
            s1 += __shfl_xor(s1, off);
            s2 += __shfl_xor(s2, off);
        }
        float mu  = s1 * (1.f/64.f);
        float var = s2 * (1.f/64.f) - mu * mu;
        float r   = rsqrtf(var + 1e-5f);
        float o   = (acc2 - mu) * r * sC + bC;
        float ov  = o > 0.f ? o : 0.f;
        h_out[(size_t)n*HID + lane] = ov;
        if (h16_out) h16_out[(size_t)n*HID + lane] = (_Float16)ov;
    }
}

// ---------------- prep: W2T transpose + selp = b_ih + sel @ W_ih[:, :64]^T ----------------
// stored PERMUTED to lstm thread order: gate g -> pos = (j<<2)|((gt&1)<<1)|(gt>>1)
__global__ __launch_bounds__(512) void prep_kernel(
    const float* __restrict__ Wih,   // [512][96]
    const float* __restrict__ bih,   // [512]
    const float* __restrict__ h2v,   // [NN][64]
    const int*   __restrict__ nidx,  // [64]
    float*       __restrict__ W2T,   // [32][512] permuted cols
    float*       __restrict__ selp)  // [64][512] permuted cols
{
    const int g  = threadIdx.x;                       // gate index 0..511
    const int j_ = g & 127, gt_ = g >> 7;
    const int pos = (j_ << 2) | ((gt_ & 1) << 1) | (gt_ >> 1);
    if (blockIdx.x == BB) {
        #pragma unroll
        for (int k = 0; k < 32; ++k)
            W2T[k * G4 + pos] = Wih[g * 96 + 64 + k];
    } else {
        const int b = blockIdx.x;
        __shared__ float hrow[64];
        if (g < 64) hrow[g] = h2v[(size_t)nidx[b] * HID + g];
        __syncthreads();
        float acc = bih[g];
        #pragma unroll
        for (int k = 0; k < 64; ++k)
            acc = fmaf(hrow[k], Wih[g * 96 + k], acc);
        selp[b * G4 + pos] = acc;
    }
}

// ---------------- xp[t][b][pos] = selp[b][pos] + x_seq[b][t] @ W2T[:,pos] ----------------
__global__ __launch_bounds__(512) void xp_kernel(
    const float* __restrict__ xseq,  // [B][T][32]
    const float* __restrict__ selp,  // [B][512] permuted
    const float* __restrict__ W2T,   // [32][512] permuted
    float*       __restrict__ xp)    // [T][B][512] permuted
{
    const int g   = threadIdx.x;
    const int row = blockIdx.x;      // row = t*64 + b
    const int t   = row >> 6;
    const int b   = row & 63;
    __shared__ float xs[32];
    if (g < 32) xs[g] = xseq[((size_t)b * TT + t) * 32 + g];
    __syncthreads();
    float acc = selp[b * G4 + g];
    #pragma unroll
    for (int k = 0; k < 32; ++k)
        acc = fmaf(xs[k], W2T[k * G4 + g], acc);
    xp[(size_t)row * G4 + g] = acc;
}

// ---------------- LSTM recurrence + final LN + fc ----------------
// 64 blocks x 256 threads (4 waves). Thread t owns TWO gates of hidden unit
// j=t>>1: types p=t&1 and p+2 (halved wave count halves per-CU DS broadcast).
__global__ __launch_bounds__(256) void lstm_kernel(
    const float* __restrict__ xp,    // [T][B][512] thread-order
    const float* __restrict__ Whh,   // [512][128]
    const float* __restrict__ bhh,   // [512]
    const float* __restrict__ lnS, const float* __restrict__ lnB,  // [128]
    const float* __restrict__ fcW,   // [1][128]
    const float* __restrict__ fcb,   // [1]
    float*       __restrict__ out)   // [64]
{
    const int t  = threadIdx.x;      // 0..255
    const int b  = blockIdx.x;
    const int p  = t & 1;
    const int j  = t >> 1;           // hidden unit 0..127
    const int gate0 = p * LH + j;            // type p   (i or f)
    const int gate1 = (p + 2) * LH + j;      // type p+2 (g or o)

    h2 wA[64], wB[64];
    {
        const float4* wf0 = (const float4*)(Whh + (size_t)gate0 * LH);
        const float4* wf1 = (const float4*)(Whh + (size_t)gate1 * LH);
        #pragma unroll
        for (int k4 = 0; k4 < 32; ++k4) {
            float4 v = wf0[k4];
            h2 a; a.x = (_Float16)v.x; a.y = (_Float16)v.y;
            h2 c2; c2.x = (_Float16)v.z; c2.y = (_Float16)v.w;
            wA[2*k4] = a; wA[2*k4+1] = c2;
            float4 u = wf1[k4];
            h2 d; d.x = (_Float16)u.x; d.y = (_Float16)u.y;
            h2 e2; e2.x = (_Float16)u.z; e2.y = (_Float16)u.w;
            wB[2*k4] = d; wB[2*k4+1] = e2;
        }
    }
    const float bg0 = bhh[gate0];
    const float bg1 = bhh[gate1];
    const float s1_ = (p == 0) ? 2.f : 1.f;
    const float a1_ = (p == 0) ? 2.f : 1.f;
    const float d1_ = (p == 0) ? -1.f : 0.f;

    __shared__ _Float16 hb[2][LH];        // fp16 h, double buffered
    __shared__ float h_final[LH];
    if (t < 64) ((unsigned int*)&hb[0][0])[t] = 0u;
    float c = 0.f;
    float h_last = 0.f;
    __syncthreads();

    float2 xv = ((const float2*)(xp + (size_t)b * G4))[t];   // t=0 slice

    auto step = [&](const _Float16* hbR, _Float16* hbW, int ts) {
        const int tn = (ts + 1 < TT) ? ts + 1 : ts;
        const float2 xn = ((const float2*)(xp + ((size_t)tn * BB + b) * G4))[t];

        float a0 = 0.f, a1 = 0.f, a2 = 0.f, a3 = 0.f;
        float e0 = 0.f, e1 = 0.f, e2 = 0.f, e3 = 0.f;
        const uint4* hb4 = (const uint4*)hbR;
        #pragma unroll
        for (int k = 0; k < 16; ++k) {
            uint4 u = hb4[k];
            h2 p0 = as_h2(u.x), p1 = as_h2(u.y), p2 = as_h2(u.z), p3 = as_h2(u.w);
            a0 = fdot2_(p0, wA[4*k+0], a0);
            a1 = fdot2_(p1, wA[4*k+1], a1);
            a2 = fdot2_(p2, wA[4*k+2], a2);
            a3 = fdot2_(p3, wA[4*k+3], a3);
            e0 = fdot2_(p0, wB[4*k+0], e0);
            e1 = fdot2_(p1, wB[4*k+1], e1);
            e2 = fdot2_(p2, wB[4*k+2], e2);
            e3 = fdot2_(p3, wB[4*k+3], e3);
        }
        float g0 = xv.x + bg0 + ((a0 + a1) + (a2 + a3));
        float g1 = xv.y + bg1 + ((e0 + e1) + (e2 + e3));

        float act0 = sigmoid_fast(g0);                                        // i or f
        float act1 = fmaf(a1_, __fdividef(1.f, 1.f + __expf(-s1_ * g1)), d1_); // g or o

        float o0 = __shfl_xor(act0, 1);
        float o1 = __shfl_xor(act1, 1);
        float iv = p ? o0 : act0;
        float fv = p ? act0 : o0;
        float gv = p ? o1 : act1;
        float ov = p ? act1 : o1;

        c = fmaf(fv, c, iv * gv);
        h_last = ov * tanh_fast(c);

        if (p == 0) hbW[j] = (_Float16)h_last;    // ds_write_b16, even lanes
        __syncthreads();

        xv = xn;
    };

    for (int ts = 0; ts < TT; ts += 2) {
        step(&hb[0][0], &hb[1][0], ts);
        step(&hb[1][0], &hb[0][0], ts + 1);
    }

    if (p == 0) h_final[j] = h_last;
    __syncthreads();
    if (t < 64) {
        float h0 = h_final[t], h1 = h_final[t + 64];
        float s1 = h0 + h1, s2 = h0*h0 + h1*h1;
        #pragma unroll
        for (int off = 32; off >= 1; off >>= 1) {
            s1 += __shfl_xor(s1, off);
            s2 += __shfl_xor(s2, off);
        }
        float mu  = s1 * (1.f/128.f);
        float var = s2 * (1.f/128.f) - mu * mu;
        float rr  = rsqrtf(var + 1e-5f);
        float pv = ((h0 - mu)*rr*lnS[t]      + lnB[t])      * fcW[t]
                 + ((h1 - mu)*rr*lnS[t + 64] + lnB[t + 64]) * fcW[t + 64];
        #pragma unroll
        for (int off = 32; off >= 1; off >>= 1) pv += __shfl_xor(pv, off);
        if (t == 0) out[b] = pv + fcb[0];
    }
}

extern "C" void kernel_launch(void* const* d_in, const int* in_sizes, int n_in,
                              void* d_out, int out_size, void* d_ws, size_t ws_size,
                              hipStream_t stream) {
    const float* x     = (const float*)d_in[0];
    const float* ea    = (const float*)d_in[1];
    const float* xseq  = (const float*)d_in[2];
    const float* linW  = (const float*)d_in[3];
    const float* linB  = (const float*)d_in[4];
    const float* mW1   = (const float*)d_in[5];
    const float* mb1   = (const float*)d_in[6];
    const float* mW2   = (const float*)d_in[7];
    const float* mb2   = (const float*)d_in[8];
    const float* eps   = (const float*)d_in[9];
    const float* lnS   = (const float*)d_in[10];
    const float* lnB   = (const float*)d_in[11];
    const float* Wih   = (const float*)d_in[12];
    const float* Whh   = (const float*)d_in[13];
    const float* bih   = (const float*)d_in[14];
    const float* bhh   = (const float*)d_in[15];
    const float* llnS  = (const float*)d_in[16];
    const float* llnB  = (const float*)d_in[17];
    const float* fcW   = (const float*)d_in[18];
    const float* fcb   = (const float*)d_in[19];
    const int*   eidx  = (const int*)d_in[20];
    const int*   nidx  = (const int*)d_in[21];
    float* out = (float*)d_out;

    const int* srcs = eidx;
    const int* dsts = eidx + NE;

    // workspace layout
    float* ws   = (float*)d_ws;
    float* agg  = ws;                              // NN*64
    float* h1   = agg  + (size_t)NN * HID;
    float* h2m  = h1   + (size_t)NN * HID;
    float* selp = h2m  + (size_t)NN * HID;         // BB*G4
    float* W2T  = selp + (size_t)BB * G4;          // 32*G4
    float* xp   = W2T  + (size_t)32 * G4;          // TT*BB*G4
    int*   deg    = (int*)(xp + (size_t)TT * BB * G4);  // NN
    int*   rowptr = deg + NN;                      // NN+1
    int*   head   = rowptr + NN + 2;               // NN
    int*   loc    = head + NN;                     // NN
    int*   bsum   = loc + NN;                      // SCB
    int*   boff   = bsum + SCB + 3;                // SCB
    int*   perm   = boff + SCB + 3;                // NE
    int*   ssrc   = perm + NE;                     // NE
    uintptr_t ep = (uintptr_t)(ssrc + NE);
    ep = (ep + 15) & ~(uintptr_t)15;
    _Float16* easort = (_Float16*)ep;              // NE*64 halfs = 102.4 MB
    _Float16* x16    = easort + (size_t)NE * HID;  // NN*64 halfs
    _Float16* h1_16  = x16 + (size_t)NN * HID;     // NN*64 halfs

    // ---- CSR build + dst-sorted fp16 edge table + x fp16 (shared by both layers) ----
    hipMemsetAsync(deg, 0, (size_t)NN * sizeof(int), stream);
    hist_kernel<<<(NE + 255) / 256, 256, 0, stream>>>(dsts, deg);
    scan1_kernel<<<SCB, 512, 0, stream>>>(deg, loc, bsum);
    scan2_kernel<<<1, 1, 0, stream>>>(bsum, boff, rowptr);
    scan3_kernel<<<SCB, 512, 0, stream>>>(loc, boff, rowptr, head);
    scatter_kernel<<<(NE + 255) / 256, 256, 0, stream>>>(srcs, dsts, head, perm, ssrc);
    permute_kernel<<<NE / 16, 256, 0, stream>>>(ea, perm, (ushort4*)easort);
    cvt16_kernel<<<NN * HID / 4 / 256, 256, 0, stream>>>(x, x16);

    // ---- layer 0 ----
    edge_agg_kernel<<<2048, 256, 0, stream>>>(x16, easort, linW, linB, rowptr, ssrc, agg);
    node_kernel<<<512, 256, 0, stream>>>(x, agg, mW1, mb1, mW2, mb2, eps, lnS, lnB, h1, h1_16);
    // ---- layer 1 ----
    edge_agg_kernel<<<2048, 256, 0, stream>>>(h1_16, easort, linW + 64*64, linB + 64, rowptr, ssrc, agg);
    node_kernel<<<512, 256, 0, stream>>>(h1, agg, mW1 + 64*64, mb1 + 64, mW2 + 64*64, mb2 + 64,
                                         eps + 1, lnS + 64, lnB + 64, h2m, (_Float16*)nullptr);
    // ---- LSTM input projection (permuted to lstm thread order) ----
    prep_kernel<<<BB + 1, 512, 0, stream>>>(Wih, bih, h2m, nidx, W2T, selp);
    xp_kernel<<<TT * BB, 512, 0, stream>>>(xseq, selp, W2T, xp);
    // ---- LSTM recurrence + head (256 threads, 2 gates/thread) ----
    lstm_kernel<<<BB, 256, 0, stream>>>(xp, Whh, bhh, llnS, llnB, fcW, fcb, out);
}